// Round 8
// baseline (366.683 us; speedup 1.0000x reference)
//
#include <hip/hip_runtime.h>
#include <math.h>

#define N_ATOMS 4096
#define N_EDGES 131072
#define PI6 0.52359877559829887f

typedef __attribute__((ext_vector_type(8))) short bf16x8;
typedef __attribute__((ext_vector_type(4))) float f32x4;

__device__ __forceinline__ float silu_f(float x){ return x / (1.f + __expf(-x)); }
__device__ __forceinline__ float sigmoid_f(float x){ return 1.f / (1.f + __expf(-x)); }
__device__ __forceinline__ float bcastf(float v, int k){
  return __int_as_float(__builtin_amdgcn_readlane(__float_as_int(v), k));
}
__device__ __forceinline__ unsigned int f2bf(float f){
  unsigned int u = __float_as_uint(f);
  return (u + 0x7FFFu + ((u>>16)&1u)) >> 16;
}
__device__ __forceinline__ bf16x8 ld8(const unsigned short* p){
  union { unsigned int u[4]; bf16x8 v; } r;
  const unsigned int* q = (const unsigned int*)p;
  r.u[0]=q[0]; r.u[1]=q[1]; r.u[2]=q[2]; r.u[3]=q[3];
  return r.v;
}

// ---------- transpose attn_w_in (384x128) and attn_w_out (128x128) ----------
__global__ __launch_bounds__(256) void transpose_kernel(
  const float* __restrict__ win, const float* __restrict__ wout,
  float* __restrict__ wt_in, float* __restrict__ wt_out){
  int idx = blockIdx.x*256 + threadIdx.x;
  if (idx < 384*128){ int i = idx>>7, k = idx&127; wt_in[k*384+i] = win[idx]; }
  else { int j = idx - 384*128; int i = j>>7, k = j&127; wt_out[k*128+i] = wout[j]; }
}

// ---------- counting sort of edges by destination ----------
__global__ void hist_kernel(const int* __restrict__ edge_index, int* __restrict__ counts){
  int e = blockIdx.x*blockDim.x + threadIdx.x;
  if (e < N_EDGES) atomicAdd(&counts[edge_index[N_EDGES + e]], 1);
}

__global__ void scan_kernel(const int* __restrict__ counts, int* __restrict__ offsets){
  __shared__ int buf[4096];
  int t = threadIdx.x; // 1024 threads
  for (int i=t;i<4096;i+=1024) buf[i]=counts[i];
  __syncthreads();
  for (int off=1; off<4096; off<<=1){
    int v[4];
    #pragma unroll
    for (int k=0;k<4;k++){ int i=t+k*1024; v[k] = (i>=off)?buf[i-off]:0; }
    __syncthreads();
    #pragma unroll
    for (int k=0;k<4;k++){ int i=t+k*1024; buf[i]+=v[k]; }
    __syncthreads();
  }
  for (int i=t;i<4096;i+=1024) offsets[i]=buf[i]-counts[i]; // exclusive
  if (t==0) offsets[4096]=buf[4095];
}

__global__ void scatter_kernel(const int* __restrict__ edge_index, const int* __restrict__ offsets,
                               int* __restrict__ cursor, int* __restrict__ edge_list){
  int e = blockIdx.x*blockDim.x + threadIdx.x;
  if (e < N_EDGES){
    int d = edge_index[N_EDGES + e];
    int pos = atomicAdd(&cursor[d], 1);
    edge_list[offsets[d] + pos] = e;
  }
}

// ---------- per-atom edge features -> F (planar [9][N_ATOMS*128]) ----------
// 512 thr = 4 edge-groups x 128 channels; readlane broadcasts.
// launch_bounds(512,4): VGPR budget 128 so w2c[64] stays in registers
// (plain (512) capped at 56 VGPR -> w2c reloaded from L1 every FMA, 4.3 GB).
__global__ __launch_bounds__(512, 4) void edge_F_kernel(
  const float* __restrict__ edge_vectors, const float* __restrict__ edge_lengths,
  const float* __restrict__ rad_w1, const float* __restrict__ rad_b1,
  const float* __restrict__ rad_w2, const float* __restrict__ rad_b2,
  const int* __restrict__ offsets, const int* __restrict__ edge_list,
  float* __restrict__ Fp)
{
  const int a = blockIdx.x, tid = threadIdx.x;
  const int g = tid >> 7;        // edge group 0..3
  const int t = tid & 127;       // channel
  const int lane = tid & 63;
  __shared__ float Fred[4][128][9];   // 18 KB

  float w2c[64], w1r[8];
  #pragma unroll
  for (int k=0;k<64;k++) w2c[k] = rad_w2[k*128 + t];
  #pragma unroll
  for (int k=0;k<8;k++)  w1r[k] = rad_w1[k*64 + lane];
  const float b1l = rad_b1[lane], b2c = rad_b2[t];
  float F9[9];
  #pragma unroll
  for (int j=0;j<9;j++) F9[j]=0.f;

  const int beg = offsets[a], end = offsets[a+1];
  for (int ei=beg+g; ei<end; ei+=4){
    int e = __builtin_amdgcn_readfirstlane(edge_list[ei]);
    float vx = edge_vectors[e*3], vy = edge_vectors[e*3+1], vz = edge_vectors[e*3+2];
    float d  = edge_lengths[e];
    float rn = sqrtf(vx*vx+vy*vy+vz*vz) + 1e-8f;
    float x = vx/rn, y = vy/rn, z = vz/rn;
    float sh[9] = {1.f, y, z, x, 3.f*z*z-1.f, x*z, y*z, x*y, x*x-y*y};
    float rb = 0.f;
    if (lane < 8){
      float cut = 0.5f*(__cosf(d*PI6)+1.f)*(d<6.f?1.f:0.f);
      rb = __sinf(d*((float)(lane+1)*PI6))/d*cut;
    }
    float pa = b1l, pb = 0.f;
    #pragma unroll
    for (int k=0;k<8;k+=2){
      pa += bcastf(rb,k)*w1r[k];
      pb += bcastf(rb,k+1)*w1r[k+1];
    }
    float r1 = silu_f(pa+pb);
    float r2a=b2c, r2b=0.f, r2c=0.f, r2d=0.f;
    #pragma unroll
    for (int k=0;k<64;k+=4){
      r2a += bcastf(r1,k  )*w2c[k  ];
      r2b += bcastf(r1,k+1)*w2c[k+1];
      r2c += bcastf(r1,k+2)*w2c[k+2];
      r2d += bcastf(r1,k+3)*w2c[k+3];
    }
    float r2 = silu_f((r2a+r2b)+(r2c+r2d));
    #pragma unroll
    for (int j=0;j<9;j++) F9[j] += r2*sh[j];
  }

  #pragma unroll
  for (int j=0;j<9;j++) Fred[g][t][j] = F9[j];
  __syncthreads();
  if (g==0){
    #pragma unroll
    for (int j=0;j<9;j++)
      Fp[j*(N_ATOMS*128) + a*128 + t] = F9[j] + Fred[1][t][j] + Fred[2][t][j] + Fred[3][t][j];
  }
}

// ---------- node update: agg -> msg MLP -> qkv ; 8 atoms, 512 threads ----------
__global__ __launch_bounds__(512) void node_kernel(
  const int* __restrict__ atomic_numbers, const float* __restrict__ atom_embed,
  const float* __restrict__ tp_w, const float* __restrict__ tp_b,
  const float* __restrict__ msg_w1, const float* __restrict__ msg_b1,
  const float* __restrict__ msg_w2, const float* __restrict__ msg_b2,
  const float* __restrict__ wt_in, const float* __restrict__ attn_b_in,
  const int* __restrict__ offsets, const float* __restrict__ Fp,
  float* __restrict__ upd_out, float* __restrict__ qkv_out)
{
  const int a0 = blockIdx.x*8, tid = threadIdx.x;
  const int g = tid >> 7, o = tid & 127;
  __shared__ float red[4][8][128];   // 16 KB
  __shared__ float combs[8][192];
  __shared__ float hids[8][128];
  __shared__ float upds[8][128];

  float acc[8];
  #pragma unroll
  for (int a8=0;a8<8;a8++) acc[a8] = 0.f;

  const float4* Fp4 = (const float4*)Fp;
  for (int c4=g*8; c4<g*8+8; c4++){
    #pragma unroll
    for (int j=0;j<9;j++){
      float4 f[8];
      #pragma unroll
      for (int a8=0;a8<8;a8++) f[a8] = Fp4[j*(N_ATOMS*32) + (a0+a8)*32 + c4];
      #pragma unroll
      for (int cc=0;cc<4;cc++){
        int c = c4*4+cc;
        int row = (j==0)? c : (j<4 ? 128 + c*3 + (j-1) : 512 + c*5 + (j-4));
        float w = tp_w[row*128+o];
        #pragma unroll
        for (int a8=0;a8<8;a8++){
          float fv = (cc==0)?f[a8].x:(cc==1)?f[a8].y:(cc==2)?f[a8].z:f[a8].w;
          acc[a8] += fv*w;
        }
      }
    }
  }
  #pragma unroll
  for (int a8=0;a8<8;a8++) red[g][a8][o] = acc[a8];
  { int a8 = tid>>6, k = tid&63;
    combs[a8][k] = atom_embed[atomic_numbers[a0+a8]*64 + k]; }
  __syncthreads();
  if (g==0){
    const float tb = tp_b[o];
    #pragma unroll
    for (int a8=0;a8<8;a8++){
      float deg = (float)(offsets[a0+a8+1]-offsets[a0+a8]);
      combs[a8][64+o] = red[0][a8][o]+red[1][a8][o]+red[2][a8][o]+red[3][a8][o] + tb*deg;
    }
  }
  __syncthreads();

  const int aA = 2*g, aB = 2*g+1;
  {
    float hA = msg_b1[o], hB = hA;
    for (int k=0;k<192;k++){
      float w = msg_w1[k*128+o];
      hA += combs[aA][k]*w; hB += combs[aB][k]*w;
    }
    hids[aA][o] = silu_f(hA); hids[aB][o] = silu_f(hB);
  }
  __syncthreads();
  {
    float uA = msg_b2[o], uB = uA;
    for (int k=0;k<128;k++){
      float w = msg_w2[k*128+o];
      uA += hids[aA][k]*w; uB += hids[aB][k]*w;
    }
    upds[aA][o]=uA; upds[aB][o]=uB;
    upd_out[(a0+aA)*128+o]=uA; upd_out[(a0+aB)*128+o]=uB;
  }
  __syncthreads();
  for (int p=0;p<3;p++){
    float qA = attn_b_in[p*128+o], qB = qA;
    for (int k=0;k<128;k++){
      float w = wt_in[k*384 + p*128 + o];
      qA += upds[aA][k]*w; qB += upds[aB][k]*w;
    }
    qkv_out[(a0+aA)*384 + p*128 + o] = qA;
    qkv_out[(a0+aB)*384 + p*128 + o] = qB;
  }
}

// ---------- MFMA flash attention: 4 heads, N=4096, D=32, bf16 matmuls ----------
// block: 32 queries x 1 head, 256 thr = 8 waves = (2 q-groups) x (2 key-halves)
__global__ __launch_bounds__(256) void attn_kernel(const float* __restrict__ qkv, float* __restrict__ att){
  const int b = blockIdx.x;
  const int h = b >> 7, qt = b & 127;      // 4 heads, 128 q-tiles of 32
  const int tid = threadIdx.x;
  const int w = tid >> 6, lane = tid & 63;
  const int wq = w & 1, wk = w >> 1;       // query group, key half
  const int l15 = lane & 15, lg = lane >> 4;
  const int n0 = qt*32;

  __shared__ unsigned short Qs[32][36];
  __shared__ unsigned short Ks[2][2][64][36];
  __shared__ unsigned short Vt[2][2][32][66];
  __shared__ unsigned short Ps[8][16][68];
  __shared__ float MB[2][64][16];

  const float scale = 0.17677669529663687f; // 1/sqrt(32)

  // ---- stage Q (scaled) ----
  {
    int qr = tid>>3, d4 = (tid&7)*4;
    const float4 qf = *(const float4*)(qkv + (size_t)(n0+qr)*384 + h*32 + d4);
    unsigned int* dst = (unsigned int*)&Qs[qr][d4];
    dst[0] = f2bf(qf.x*scale) | (f2bf(qf.y*scale)<<16);
    dst[1] = f2bf(qf.z*scale) | (f2bf(qf.w*scale)<<16);
  }

  // staging thread mapping: half hf = tid>>7 stages tile (hf*32 + t)
  const int hf = tid >> 7, u = tid & 127;
  const int skey = u >> 1, sd16 = (u & 1)*16;
  float4 kA,kB,kC,kD, vA,vB,vC,vD;

  #define LOADG(T) { \
    const float* kp = qkv + (size_t)(((hf*32+(T))*64 + skey))*384 + 128 + h*32 + sd16; \
    kA = *(const float4*)kp;        kB = *(const float4*)(kp+4); \
    kC = *(const float4*)(kp+8);    kD = *(const float4*)(kp+12); \
    const float* vp = kp + 128; \
    vA = *(const float4*)vp;        vB = *(const float4*)(vp+4); \
    vC = *(const float4*)(vp+8);    vD = *(const float4*)(vp+12); }

  #define WRITEL(BUF) { \
    unsigned int* kdst = (unsigned int*)&Ks[BUF][hf][skey][sd16]; \
    kdst[0]=f2bf(kA.x)|(f2bf(kA.y)<<16); kdst[1]=f2bf(kA.z)|(f2bf(kA.w)<<16); \
    kdst[2]=f2bf(kB.x)|(f2bf(kB.y)<<16); kdst[3]=f2bf(kB.z)|(f2bf(kB.w)<<16); \
    kdst[4]=f2bf(kC.x)|(f2bf(kC.y)<<16); kdst[5]=f2bf(kC.z)|(f2bf(kC.w)<<16); \
    kdst[6]=f2bf(kD.x)|(f2bf(kD.y)<<16); kdst[7]=f2bf(kD.z)|(f2bf(kD.w)<<16); \
    Vt[BUF][hf][sd16+ 0][skey]=(unsigned short)f2bf(vA.x); \
    Vt[BUF][hf][sd16+ 1][skey]=(unsigned short)f2bf(vA.y); \
    Vt[BUF][hf][sd16+ 2][skey]=(unsigned short)f2bf(vA.z); \
    Vt[BUF][hf][sd16+ 3][skey]=(unsigned short)f2bf(vA.w); \
    Vt[BUF][hf][sd16+ 4][skey]=(unsigned short)f2bf(vB.x); \
    Vt[BUF][hf][sd16+ 5][skey]=(unsigned short)f2bf(vB.y); \
    Vt[BUF][hf][sd16+ 6][skey]=(unsigned short)f2bf(vB.z); \
    Vt[BUF][hf][sd16+ 7][skey]=(unsigned short)f2bf(vB.w); \
    Vt[BUF][hf][sd16+ 8][skey]=(unsigned short)f2bf(vC.x); \
    Vt[BUF][hf][sd16+ 9][skey]=(unsigned short)f2bf(vC.y); \
    Vt[BUF][hf][sd16+10][skey]=(unsigned short)f2bf(vC.z); \
    Vt[BUF][hf][sd16+11][skey]=(unsigned short)f2bf(vC.w); \
    Vt[BUF][hf][sd16+12][skey]=(unsigned short)f2bf(vD.x); \
    Vt[BUF][hf][sd16+13][skey]=(unsigned short)f2bf(vD.y); \
    Vt[BUF][hf][sd16+14][skey]=(unsigned short)f2bf(vD.z); \
    Vt[BUF][hf][sd16+15][skey]=(unsigned short)f2bf(vD.w); }

  LOADG(0);
  WRITEL(0);
  __syncthreads();

  // A-fragment for Q (after barrier so Qs is complete)
  bf16x8 aQ = ld8(&Qs[wq*16 + l15][lg*8]);

  float m[4] = {-3e38f,-3e38f,-3e38f,-3e38f};
  float su[4] = {0.f,0.f,0.f,0.f};
  f32x4 oacc[2] = {{0.f,0.f,0.f,0.f},{0.f,0.f,0.f,0.f}};

  for (int t=0; t<32; t++){
    const int cur = t&1;
    if (t<31) LOADG(t+1);

    // QK^T: 4 MFMA, S tile 16q x 64k
    f32x4 s[4];
    #pragma unroll
    for (int n=0;n<4;n++){
      bf16x8 bK = ld8(&Ks[cur][wk][n*16+l15][lg*8]);
      f32x4 z = {0.f,0.f,0.f,0.f};
      s[n] = __builtin_amdgcn_mfma_f32_16x16x32_bf16(aQ, bK, z, 0,0,0);
    }

    // online softmax
    float csc[4], psum[4];
    #pragma unroll
    for (int r=0;r<4;r++){
      float mloc = fmaxf(fmaxf(s[0][r], s[1][r]), fmaxf(s[2][r], s[3][r]));
      #pragma unroll
      for (int off=1; off<16; off<<=1) mloc = fmaxf(mloc, __shfl_xor(mloc, off, 64));
      float mn = fmaxf(m[r], mloc);
      csc[r] = __expf(m[r] - mn);
      m[r] = mn;
      psum[r] = 0.f;
    }
    #pragma unroll
    for (int n=0;n<4;n++){
      #pragma unroll
      for (int r=0;r<4;r++){
        float p = __expf(s[n][r] - m[r]);
        psum[r] += p;
        Ps[w][lg*4+r][n*16+l15] = (unsigned short)f2bf(p);
      }
    }
    #pragma unroll
    for (int r=0;r<4;r++){
      #pragma unroll
      for (int off=1; off<16; off<<=1) psum[r] += __shfl_xor(psum[r], off, 64);
      su[r] = su[r]*csc[r] + psum[r];
    }
    #pragma unroll
    for (int nd=0;nd<2;nd++){
      #pragma unroll
      for (int r=0;r<4;r++) oacc[nd][r] *= csc[r];
    }

    // PV: O(16q x 32d) += P(16x64) * V(64x32)
    #pragma unroll
    for (int c=0;c<2;c++){
      bf16x8 aP = ld8(&Ps[w][l15][c*32 + lg*8]);
      #pragma unroll
      for (int nd=0;nd<2;nd++){
        bf16x8 bV = ld8(&Vt[cur][wk][nd*16+l15][c*32 + lg*8]);
        oacc[nd] = __builtin_amdgcn_mfma_f32_16x16x32_bf16(aP, bV, oacc[nd], 0,0,0);
      }
    }

    __syncthreads();
    if (t<31) WRITEL((t+1)&1);
    __syncthreads();
  }

  // merge key-halves: wk=1 publishes, wk=0 merges and writes out
  if (wk==1){
    #pragma unroll
    for (int r=0;r<4;r++){ MB[wq][lane][r] = m[r]; MB[wq][lane][4+r] = su[r]; }
    #pragma unroll
    for (int nd=0;nd<2;nd++)
      #pragma unroll
      for (int r=0;r<4;r++) MB[wq][lane][8+nd*4+r] = oacc[nd][r];
  }
  __syncthreads();
  if (wk==0){
    #pragma unroll
    for (int r=0;r<4;r++){
      float m1 = MB[wq][lane][r], s1 = MB[wq][lane][4+r];
      float mf = fmaxf(m[r], m1);
      float c0 = __expf(m[r]-mf), c1 = __expf(m1-mf);
      float stot = su[r]*c0 + s1*c1;
      float inv = 1.f/stot;
      #pragma unroll
      for (int nd=0;nd<2;nd++){
        float o = oacc[nd][r]*c0 + MB[wq][lane][8+nd*4+r]*c1;
        att[(size_t)(n0 + wq*16 + lg*4 + r)*128 + h*32 + nd*16 + l15] = o*inv;
      }
    }
  }
  #undef LOADG
  #undef WRITEL
}

// ---------- epilogue: 8 atoms, 512 threads, LDS-staged operands ----------
__global__ __launch_bounds__(512) void final_kernel(
  const float* __restrict__ att, const float* __restrict__ upd,
  const float* __restrict__ wt_out, const float* __restrict__ attn_b_out,
  const float* __restrict__ gate_w, const float* __restrict__ gate_b,
  const float* __restrict__ out_w, const float* __restrict__ out_b,
  float* __restrict__ out)
{
  const int a0 = blockIdx.x*8, tid = threadIdx.x;
  const int g = tid >> 7, o = tid & 127;
  __shared__ float att_s[8][128], upd_s[8][128], tmps[8][128];
  for (int i=tid; i<1024; i+=512){
    int a8 = i>>7, k = i&127;
    att_s[a8][k] = att[(a0+a8)*128+k];
    upd_s[a8][k] = upd[(a0+a8)*128+k];
  }
  __syncthreads();
  const int aA = 2*g, aB = 2*g+1;
  float a2A = attn_b_out[o], a2B = a2A;
  float gA = gate_b[o], gB = gA;
  for (int k=0;k<128;k++){
    float wa = wt_out[k*128+o];
    float wg = gate_w[k*128+o];
    a2A += att_s[aA][k]*wa; a2B += att_s[aB][k]*wa;
    gA  += upd_s[aA][k]*wg; gB  += upd_s[aB][k]*wg;
  }
  gA = sigmoid_f(gA); gB = sigmoid_f(gB);
  tmps[aA][o] = gA*a2A + (1.f-gA)*upd_s[aA][o];
  tmps[aB][o] = gB*a2B + (1.f-gB)*upd_s[aB][o];
  __syncthreads();
  float ouA = out_b[o], ouB = ouA;
  for (int k=0;k<128;k++){
    float w = out_w[k*128+o];
    ouA += tmps[aA][k]*w; ouB += tmps[aB][k]*w;
  }
  out[(a0+aA)*128+o] = ouA;
  out[(a0+aB)*128+o] = ouB;
}

extern "C" void kernel_launch(void* const* d_in, const int* in_sizes, int n_in,
                              void* d_out, int out_size, void* d_ws, size_t ws_size,
                              hipStream_t stream){
  const int*   atomic_numbers = (const int*)  d_in[0];
  const int*   edge_index     = (const int*)  d_in[2];
  const float* edge_vectors   = (const float*)d_in[3];
  const float* edge_lengths   = (const float*)d_in[4];
  const float* atom_embed     = (const float*)d_in[5];
  const float* rad_w1 = (const float*)d_in[6];
  const float* rad_b1 = (const float*)d_in[7];
  const float* rad_w2 = (const float*)d_in[8];
  const float* rad_b2 = (const float*)d_in[9];
  const float* tp_w   = (const float*)d_in[10];
  const float* tp_b   = (const float*)d_in[11];
  const float* msg_w1 = (const float*)d_in[12];
  const float* msg_b1 = (const float*)d_in[13];
  const float* msg_w2 = (const float*)d_in[14];
  const float* msg_b2 = (const float*)d_in[15];
  const float* attn_w_in  = (const float*)d_in[16];
  const float* attn_b_in  = (const float*)d_in[17];
  const float* attn_w_out = (const float*)d_in[18];
  const float* attn_b_out = (const float*)d_in[19];
  const float* gate_w = (const float*)d_in[20];
  const float* gate_b = (const float*)d_in[21];
  const float* out_w  = (const float*)d_in[22];
  const float* out_b  = (const float*)d_in[23];

  // workspace layout (bytes)
  char* ws = (char*)d_ws;
  int* counts    = (int*)(ws);             // [0, 16384)
  int* cursor    = (int*)(ws + 16384);     // [16384, 32768)
  int* offsets   = (int*)(ws + 32768);     // [32768, 49156)  4097 ints
  int* edge_list = (int*)(ws + 53248);     // [53248, 577536)
  float* wt_in   = (float*)(ws + 577536);  // 128x384
  float* wt_out  = (float*)(ws + 774144);  // 128x128
  float* Fp      = (float*)(ws + 839680);  // [9][4096*128] = 18.9 MB
  float* att     = (float*)(ws + 839680);  // aliases Fp (dead before attn)
  float* upd     = (float*)(ws + 19714048);// 2 MB
  float* qkv     = (float*)(ws + 21811200);// 6.3 MB  (end 28102656)

  transpose_kernel<<<256, 256, 0, stream>>>(attn_w_in, attn_w_out, wt_in, wt_out);
  hipMemsetAsync(ws, 0, 32768, stream);  // counts + cursor
  hist_kernel<<<(N_EDGES+255)/256, 256, 0, stream>>>(edge_index, counts);
  scan_kernel<<<1, 1024, 0, stream>>>(counts, offsets);
  scatter_kernel<<<(N_EDGES+255)/256, 256, 0, stream>>>(edge_index, offsets, cursor, edge_list);
  edge_F_kernel<<<N_ATOMS, 512, 0, stream>>>(edge_vectors, edge_lengths,
      rad_w1, rad_b1, rad_w2, rad_b2, offsets, edge_list, Fp);
  node_kernel<<<N_ATOMS/8, 512, 0, stream>>>(atomic_numbers, atom_embed,
      tp_w, tp_b, msg_w1, msg_b1, msg_w2, msg_b2, wt_in, attn_b_in,
      offsets, Fp, upd, qkv);
  attn_kernel<<<512, 256, 0, stream>>>(qkv, att);
  final_kernel<<<N_ATOMS/8, 512, 0, stream>>>(att, upd, wt_out, attn_b_out,
      gate_w, gate_b, out_w, out_b, (float*)d_out);
}